// Round 8
// baseline (632.769 us; speedup 1.0000x reference)
//
#include <hip/hip_runtime.h>
#include <hip/hip_bf16.h>

#define EPS 1e-6f
typedef unsigned short b16;
typedef __attribute__((ext_vector_type(8))) short v8s;
typedef __attribute__((ext_vector_type(4))) float v4f;

typedef const __attribute__((address_space(1))) void* gptr_t;
typedef __attribute__((address_space(3))) void* lptr_t;

__device__ __forceinline__ b16 f2b(float f) {
    __hip_bfloat16 h = __float2bfloat16(f);
    return *reinterpret_cast<b16*>(&h);
}
__device__ __forceinline__ float siluf(float x){ return x / (1.f + __expf(-x)); }

// async global->LDS, 16B per lane; LDS dest = wave-uniform base + lane*16
__device__ __forceinline__ void gll16(const b16* g, b16* l) {
    __builtin_amdgcn_global_load_lds((gptr_t)g, (lptr_t)l, 16, 0, 0);
}

// 64-lane sum reduce: levels 1,2,4,8 on VALU (DPP row_ror), xor16 ds_swizzle, xor32 shfl
__device__ __forceinline__ float red64(float s) {
    int t;
    t = __builtin_amdgcn_update_dpp(0, __float_as_int(s), 0x121, 0xF, 0xF, false);
    s += __int_as_float(t);   // + ror1
    t = __builtin_amdgcn_update_dpp(0, __float_as_int(s), 0x122, 0xF, 0xF, false);
    s += __int_as_float(t);   // + ror2
    t = __builtin_amdgcn_update_dpp(0, __float_as_int(s), 0x124, 0xF, 0xF, false);
    s += __int_as_float(t);   // + ror4
    t = __builtin_amdgcn_update_dpp(0, __float_as_int(s), 0x128, 0xF, 0xF, false);
    s += __int_as_float(t);   // + ror8 -> row(16) sum in all lanes
    s += __int_as_float(__builtin_amdgcn_ds_swizzle(__float_as_int(s), 0x401F)); // xor16
    s += __shfl_xor(s, 32, 64);                                                  // xor32
    return s;
}

// ---- skip weight transpose: w [ic][128] fp32 -> [oc][ic] bf16 ----
template<int IC>
__global__ void __launch_bounds__(256) k_wt(const float* __restrict__ w, b16* __restrict__ o, int tot) {
    int i = blockIdx.x*256 + threadIdx.x;
    if (i >= tot) return;
    int ic = i % IC; int oc = (i / IC) & 127; int tap = i / (IC*128);
    o[i] = f2b(w[(tap*IC + ic)*128 + oc]);
}

// ---- conv weight blocked transpose: w [tap][ic][128] fp32 -> [tap][icb][oc][32] bf16 ----
template<int IC>
__global__ void __launch_bounds__(256) k_wtb(const float* __restrict__ w, b16* __restrict__ o, int tot) {
    int i = blockIdx.x*256 + threadIdx.x;
    if (i >= tot) return;
    constexpr int ICB = IC/32;
    int icl = i & 31;
    int oc  = (i >> 5) & 127;
    int r   = i >> 12;              // tap*ICB + icb
    int tap = r / ICB, icb = r % ICB;
    o[i] = f2b(w[(tap*IC + icb*32 + icl)*128 + oc]);
}

// ---- A: LN(64)+affine+silu+mask, 2x2x2 masked mean pool; h -> padded buffer ----
// mask-skip: inactive voxels (70%) contribute nothing; mask is wave-uniform
// (lane = channel), so the skip is a uniform branch -> no feats load, no LN.
__global__ void __launch_bounds__(256) k_ln_down(
    const float* __restrict__ feats, const int* __restrict__ mask,
    const float* __restrict__ gamma, const float* __restrict__ beta,
    b16* __restrict__ h_ds_pad, b16* __restrict__ x_ds, float* __restrict__ cnt_out)
{
    int wave = (blockIdx.x * 256 + threadIdx.x) >> 6;   // cell id, 0..131071
    int lane = threadIdx.x & 63;
    int x = wave & 31, y = (wave >> 5) & 31, z = (wave >> 10) & 31, b = wave >> 15;
    float g = gamma[lane], be = beta[lane];
    float hacc = 0.f, xacc = 0.f, cnt = 0.f;
    #pragma unroll
    for (int i = 0; i < 8; ++i) {
        int zz = 2*z + (i>>2), yy = 2*y + ((i>>1)&1), xx = 2*x + (i&1);
        int vox = ((b*64 + zz)*64 + yy)*64 + xx;
        int m = mask[vox];
        if (m != 0) {
            float val = feats[vox*64 + lane];
            float s1 = red64(val);
            float s2 = red64(val*val);
            float mu = s1 * (1.f/64.f);
            float var = fmaxf(s2 * (1.f/64.f) - mu*mu, 0.f);
            float h = (val - mu) * rsqrtf(var + EPS) * g + be;
            h = siluf(h);
            hacc += h; xacc += val; cnt += 1.f;
        }
    }
    float inv = 1.f / fmaxf(cnt, 1.f);
    long vp = ((long)(b*34 + z+1)*34 + (y+1))*34 + (x+1);
    h_ds_pad[vp*64 + lane] = f2b(hacc * inv);
    x_ds[(long)wave*64 + lane] = f2b(xacc * inv);
    if (lane == 0) cnt_out[wave] = cnt;
}

// ---- conv1: DMA-staged double-buffer, 4 blk/CU (r7-verified structure) ----
// block = 256 thr = 4 waves; C-tile M=128 (4 y-rows x 32 x), N=128 oc.
// Wave owns 32 rows x 128 oc (LN epilogue needs all oc in-wave).
__global__ void __launch_bounds__(256, 4) k_conv1(
    const b16* __restrict__ inp,      // padded [b][34][34][34][64] bf16
    const b16* __restrict__ wt,       // [tap][icb][128 oc][32 ic] bf16
    const float* __restrict__ bias,
    const float* __restrict__ cnt,
    b16* __restrict__ h2out)          // padded bf16 out
{
    constexpr int IC = 64, ICB = 2, NK = 54;
    __shared__ b16 lA[2][4096];
    __shared__ b16 lB[2][4096];

    int bid = ((blockIdx.x & 7) << 7) | (blockIdx.x >> 3);   // XCD swizzle
    int y0 = (bid & 7) << 2;
    int z  = (bid >> 3) & 31;
    int b  = bid >> 8;
    int t  = threadIdx.x;
    int lane = t & 63;
    int w = t >> 6;
    int col = lane & 15;
    int quad = lane >> 4;

    const b16* gAsrc[2];
    const b16* gBsrc[2];
    {
        int vsub = lane >> 2;
        int s    = lane & 3;
        #pragma unroll
        for (int j = 0; j < 2; ++j) {
            int x  = j*16 + vsub;
            int cA = (s - (x >> 1)) & 3;
            gAsrc[j] = inp + ((long)((b*34 + z)*34 + (y0 + w))*34 + x)*IC + cA*8;
            int cB = (s - (vsub >> 1)) & 3;
            gBsrc[j] = wt + (w*32 + j*16 + vsub)*32 + cB*8;
        }
    }

    int so   = ((quad + (col>>1)) & 3) * 8;
    int aoff = w*1024 + col*32 + so;
    int boff = col*32 + so;

    v4f acc[2][8];
    #pragma unroll
    for (int tl=0;tl<2;++tl)
        #pragma unroll
        for (int n=0;n<8;++n) acc[tl][n] = (v4f){0.f,0.f,0.f,0.f};

    long offAn = 0;
    int icbn = 0, kxn = 0, kyn = 0;
    auto advance = [&]() {
        ++icbn; offAn += 32;
        if (icbn == ICB) {
            icbn = 0; ++kxn;
            if (kxn == 3) {
                kxn = 0; ++kyn;
                if (kyn == 3) { kyn = 0; offAn += (long)(34*34 - 2*34 - 3)*IC; }
                else          {           offAn += (long)(34 - 3)*IC; }
            }
        }
    };
    auto stage = [&](long offA, long offB, int buf) {
        #pragma unroll
        for (int j = 0; j < 2; ++j) {
            gll16(gAsrc[j] + offA, &lA[buf][w*1024 + j*512]);
            gll16(gBsrc[j] + offB, &lB[buf][w*1024 + j*512]);
        }
    };

    stage(0, 0, 0);
    advance();
    long offBn = 4096;
    __syncthreads();

    int cur = 0;
    for (int k = 0; k < NK; ++k) {
        if (k + 1 < NK) { stage(offAn, offBn, cur ^ 1); advance(); offBn += 4096; }
        v8s a0 = *(const v8s*)(&lA[cur][aoff]);
        v8s a1 = *(const v8s*)(&lA[cur][aoff + 512]);
        #pragma unroll
        for (int n = 0; n < 8; ++n) {
            v8s bb = *(const v8s*)(&lB[cur][n*512 + boff]);
            acc[0][n] = __builtin_amdgcn_mfma_f32_16x16x32_bf16(a0, bb, acc[0][n], 0,0,0);
            acc[1][n] = __builtin_amdgcn_mfma_f32_16x16x32_bf16(a1, bb, acc[1][n], 0,0,0);
        }
        __syncthreads();
        cur ^= 1;
    }

    int yrow = y0 + w;
    long cellrow = ((long)(b*32+z)*32 + yrow)*32;

    float bv[8];
    #pragma unroll
    for (int n=0;n<8;++n) bv[n] = bias[n*16+col];

    long prow = ((long)(b*34 + z+1)*34 + (yrow+1))*34 + 1;

    #pragma unroll
    for (int tl=0; tl<2; ++tl) {
        // bias + LN(128, no affine) + silu + mask -> padded bf16
        float s1[4], s2[4];
        #pragma unroll
        for (int r=0;r<4;++r){
            float a=0.f, q=0.f;
            #pragma unroll
            for (int n=0;n<8;++n){ float v = acc[tl][n][r] + bv[n]; a+=v; q+=v*v; }
            s1[r]=a; s2[r]=q;
        }
        #pragma unroll
        for (int off=1; off<16; off<<=1){
            #pragma unroll
            for (int r=0;r<4;++r){ s1[r]+=__shfl_xor(s1[r],off); s2[r]+=__shfl_xor(s2[r],off); }
        }
        #pragma unroll
        for (int r=0;r<4;++r){
            int row = quad*4 + r;
            int x = tl*16 + row;
            float c = cnt[cellrow + x];
            float mu = s1[r]*(1.f/128.f);
            float var = fmaxf(s2[r]*(1.f/128.f) - mu*mu, 0.f);
            float rs = rsqrtf(var + EPS);
            bool act = c > 0.f;
            #pragma unroll
            for (int n=0;n<8;++n){
                float v = acc[tl][n][r] + bv[n];
                float hv = act ? siluf((v-mu)*rs) : 0.f;
                h2out[(prow + x)*128 + n*16 + col] = f2b(hv);
            }
        }
    }
}

// ---- conv2: DMA-staged, 4 blk/CU, 2x2 wave-split (wave = 64 rows x 64 oc) ----
// B-tile read redundancy 4x -> 2x: LDS fragment reads 40 -> 32 KB per K-step.
// Tile bases stay multiples of 16 -> verified rotation-slot formula invariant.
__global__ void __launch_bounds__(256, 4) k_conv2(
    const b16* __restrict__ inp,      // padded [b][34][34][34][128] bf16
    const b16* __restrict__ wt,       // [tap][icb][128 oc][32 ic] bf16
    const float* __restrict__ bias,
    const float* __restrict__ cnt,
    const b16* __restrict__ x_ds,     // [cell][64]
    const b16* __restrict__ wst,      // [128 oc][64 ic]
    const float* __restrict__ b_skip,
    float* __restrict__ out)          // fp32 [cell][128]
{
    constexpr int IC = 128, ICB = 4, NK = 108;
    __shared__ b16 lA[2][4096];
    __shared__ b16 lB[2][4096];

    int bid = ((blockIdx.x & 7) << 7) | (blockIdx.x >> 3);   // XCD swizzle
    int y0 = (bid & 7) << 2;
    int z  = (bid >> 3) & 31;
    int b  = bid >> 8;
    int t  = threadIdx.x;
    int lane = t & 63;
    int w = t >> 6;
    int col = lane & 15;
    int quad = lane >> 4;
    int wr = w >> 1;                  // row-half: rows [wr*64, wr*64+64)
    int wc = w & 1;                   // oc-half:  oc   [wc*64, wc*64+64)

    // staging identical to r7 (uses w for A y-row and B oc-range)
    const b16* gAsrc[2];
    const b16* gBsrc[2];
    {
        int vsub = lane >> 2;
        int s    = lane & 3;
        #pragma unroll
        for (int j = 0; j < 2; ++j) {
            int x  = j*16 + vsub;
            int cA = (s - (x >> 1)) & 3;
            gAsrc[j] = inp + ((long)((b*34 + z)*34 + (y0 + w))*34 + x)*IC + cA*8;
            int cB = (s - (vsub >> 1)) & 3;
            gBsrc[j] = wt + (w*32 + j*16 + vsub)*32 + cB*8;
        }
    }

    int so   = ((quad + (col>>1)) & 3) * 8;
    int aoff = wr*2048 + col*32 + so;     // + rt*512
    int boff = wc*2048 + col*32 + so;     // + ct*512

    v4f acc[4][4];
    #pragma unroll
    for (int rt=0;rt<4;++rt)
        #pragma unroll
        for (int ct=0;ct<4;++ct) acc[rt][ct] = (v4f){0.f,0.f,0.f,0.f};

    long offAn = 0;
    int icbn = 0, kxn = 0, kyn = 0;
    auto advance = [&]() {
        ++icbn; offAn += 32;
        if (icbn == ICB) {
            icbn = 0; ++kxn;
            if (kxn == 3) {
                kxn = 0; ++kyn;
                if (kyn == 3) { kyn = 0; offAn += (long)(34*34 - 2*34 - 3)*IC; }
                else          {           offAn += (long)(34 - 3)*IC; }
            }
        }
    };
    auto stage = [&](long offA, long offB, int buf) {
        #pragma unroll
        for (int j = 0; j < 2; ++j) {
            gll16(gAsrc[j] + offA, &lA[buf][w*1024 + j*512]);
            gll16(gBsrc[j] + offB, &lB[buf][w*1024 + j*512]);
        }
    };

    stage(0, 0, 0);
    advance();
    long offBn = 4096;
    __syncthreads();

    int cur = 0;
    for (int k = 0; k < NK; ++k) {
        if (k + 1 < NK) { stage(offAn, offBn, cur ^ 1); advance(); offBn += 4096; }
        v8s a[4], bb[4];
        #pragma unroll
        for (int rt = 0; rt < 4; ++rt) a[rt]  = *(const v8s*)(&lA[cur][aoff + rt*512]);
        #pragma unroll
        for (int ct = 0; ct < 4; ++ct) bb[ct] = *(const v8s*)(&lB[cur][boff + ct*512]);
        #pragma unroll
        for (int ct = 0; ct < 4; ++ct)
            #pragma unroll
            for (int rt = 0; rt < 4; ++rt)
                acc[rt][ct] = __builtin_amdgcn_mfma_f32_16x16x32_bf16(a[rt], bb[ct], acc[rt][ct], 0,0,0);
        __syncthreads();
        cur ^= 1;
    }

    long cell0 = ((long)(b*32 + z)*32 + y0)*32;   // cell(v) = cell0 + v, v in [0,128)

    // skip GEMM: x_ds[cell][64] @ wst[128][64]^T folded into accumulators
    {
        const b16* WS = wst + (wc*64 + col)*64 + quad*8;
        #pragma unroll
        for (int rt = 0; rt < 4; ++rt) {
            const b16* X = x_ds + (cell0 + wr*64 + rt*16 + col)*64 + quad*8;
            #pragma unroll
            for (int s = 0; s < 2; ++s) {
                v8s a = *(const v8s*)(X + s*32);
                #pragma unroll
                for (int ct = 0; ct < 4; ++ct) {
                    v8s bb = *(const v8s*)(WS + ct*16*64 + s*32);
                    acc[rt][ct] = __builtin_amdgcn_mfma_f32_16x16x32_bf16(a, bb, acc[rt][ct], 0,0,0);
                }
            }
        }
    }

    float bv[4];
    #pragma unroll
    for (int ct = 0; ct < 4; ++ct) {
        int oc = wc*64 + ct*16 + col;
        bv[ct] = bias[oc] + b_skip[oc];
    }

    #pragma unroll
    for (int rt = 0; rt < 4; ++rt) {
        #pragma unroll
        for (int r = 0; r < 4; ++r) {
            int v = wr*64 + rt*16 + quad*4 + r;
            long cell = cell0 + v;
            float c = cnt[cell];
            bool act = c > 0.f;
            #pragma unroll
            for (int ct = 0; ct < 4; ++ct) {
                float vv = acc[rt][ct][r] + bv[ct];
                out[cell*128 + wc*64 + ct*16 + col] = act ? vv : 0.f;
            }
        }
    }
}

extern "C" void kernel_launch(void* const* d_in, const int* in_sizes, int n_in,
                              void* d_out, int out_size, void* d_ws, size_t ws_size,
                              hipStream_t stream) {
    const float* feats  = (const float*)d_in[0];
    const int*   mask   = (const int*)  d_in[1];
    const float* gamma1 = (const float*)d_in[2];
    const float* beta1  = (const float*)d_in[3];
    const float* w1     = (const float*)d_in[4];
    const float* b1     = (const float*)d_in[5];
    const float* w2     = (const float*)d_in[6];
    const float* b2     = (const float*)d_in[7];
    const float* w_skip = (const float*)d_in[8];
    const float* b_skip = (const float*)d_in[9];
    float* out = (float*)d_out;

    char* ws = (char*)d_ws;
    b16*   h_ds_pad = (b16*)(ws);                        // 4*34^3*64*2  = 20,123,648
    b16*   h2_pad   = (b16*)(ws + 20123648);             // 4*34^3*128*2 = 40,247,296
    b16*   x_ds     = (b16*)(ws + 60370944);             // 16,777,216
    float* cnt      = (float*)(ws + 77148160);           // 524,288
    b16*   w1t      = (b16*)(ws + 77672448);             // 442,368
    b16*   w2t      = (b16*)(ws + 78114816);             // 884,736
    b16*   wst      = (b16*)(ws + 78999552);             // 16,384

    // zero halos (interior fully overwritten each launch)
    hipMemsetAsync(h_ds_pad, 0, 20123648, stream);
    hipMemsetAsync(h2_pad,   0, 40247296, stream);

    const int n_w1 = 27*64*128;    // 221184
    const int n_w2 = 27*128*128;   // 442368
    const int n_ws = 64*128;       // 8192
    k_wtb<64> <<<(n_w1 + 255)/256, 256, 0, stream>>>(w1, w1t, n_w1);
    k_wtb<128><<<(n_w2 + 255)/256, 256, 0, stream>>>(w2, w2t, n_w2);
    k_wt<64>  <<<(n_ws + 255)/256, 256, 0, stream>>>(w_skip, wst, n_ws);

    k_ln_down<<<32768, 256, 0, stream>>>(feats, mask, gamma1, beta1, h_ds_pad, x_ds, cnt);

    k_conv1<<<1024, 256, 0, stream>>>(h_ds_pad, w1t, b1, cnt, h2_pad);
    k_conv2<<<1024, 256, 0, stream>>>(h2_pad, w2t, b2, cnt, x_ds, wst, b_skip, out);
}

// Round 9
// 629.659 us; speedup vs baseline: 1.0049x; 1.0049x over previous
//
#include <hip/hip_runtime.h>
#include <hip/hip_bf16.h>

#define EPS 1e-6f
typedef unsigned short b16;
typedef __attribute__((ext_vector_type(8))) short v8s;
typedef __attribute__((ext_vector_type(4))) float v4f;

typedef const __attribute__((address_space(1))) void* gptr_t;
typedef __attribute__((address_space(3))) void* lptr_t;

__device__ __forceinline__ b16 f2b(float f) {
    __hip_bfloat16 h = __float2bfloat16(f);
    return *reinterpret_cast<b16*>(&h);
}
__device__ __forceinline__ float siluf(float x){ return x / (1.f + __expf(-x)); }

// async global->LDS, 16B per lane; LDS dest = wave-uniform base + lane*16
__device__ __forceinline__ void gll16(const b16* g, b16* l) {
    __builtin_amdgcn_global_load_lds((gptr_t)g, (lptr_t)l, 16, 0, 0);
}

// 64-lane sum reduce: levels 1,2,4,8 on VALU (DPP row_ror), xor16 ds_swizzle, xor32 shfl
__device__ __forceinline__ float red64(float s) {
    int t;
    t = __builtin_amdgcn_update_dpp(0, __float_as_int(s), 0x121, 0xF, 0xF, false);
    s += __int_as_float(t);   // + ror1
    t = __builtin_amdgcn_update_dpp(0, __float_as_int(s), 0x122, 0xF, 0xF, false);
    s += __int_as_float(t);   // + ror2
    t = __builtin_amdgcn_update_dpp(0, __float_as_int(s), 0x124, 0xF, 0xF, false);
    s += __int_as_float(t);   // + ror4
    t = __builtin_amdgcn_update_dpp(0, __float_as_int(s), 0x128, 0xF, 0xF, false);
    s += __int_as_float(t);   // + ror8 -> row(16) sum in all lanes
    s += __int_as_float(__builtin_amdgcn_ds_swizzle(__float_as_int(s), 0x401F)); // xor16
    s += __shfl_xor(s, 32, 64);                                                  // xor32
    return s;
}

// ---- skip weight transpose: w [ic][128] fp32 -> [oc][ic] bf16 ----
template<int IC>
__global__ void __launch_bounds__(256) k_wt(const float* __restrict__ w, b16* __restrict__ o, int tot) {
    int i = blockIdx.x*256 + threadIdx.x;
    if (i >= tot) return;
    int ic = i % IC; int oc = (i / IC) & 127; int tap = i / (IC*128);
    o[i] = f2b(w[(tap*IC + ic)*128 + oc]);
}

// ---- conv weight blocked transpose: w [tap][ic][128] fp32 -> [tap][icb][oc][32] bf16 ----
template<int IC>
__global__ void __launch_bounds__(256) k_wtb(const float* __restrict__ w, b16* __restrict__ o, int tot) {
    int i = blockIdx.x*256 + threadIdx.x;
    if (i >= tot) return;
    constexpr int ICB = IC/32;
    int icl = i & 31;
    int oc  = (i >> 5) & 127;
    int r   = i >> 12;              // tap*ICB + icb
    int tap = r / ICB, icb = r % ICB;
    o[i] = f2b(w[(tap*IC + icb*32 + icl)*128 + oc]);
}

// ---- A: LN(64)+affine+silu+mask, 2x2x2 masked mean pool; h -> padded buffer ----
// mask-skip: inactive voxels (70%) contribute nothing; mask is wave-uniform
// (lane = channel), so the skip is a uniform branch -> no feats load, no LN.
__global__ void __launch_bounds__(256) k_ln_down(
    const float* __restrict__ feats, const int* __restrict__ mask,
    const float* __restrict__ gamma, const float* __restrict__ beta,
    b16* __restrict__ h_ds_pad, b16* __restrict__ x_ds, float* __restrict__ cnt_out)
{
    int wave = (blockIdx.x * 256 + threadIdx.x) >> 6;   // cell id, 0..131071
    int lane = threadIdx.x & 63;
    int x = wave & 31, y = (wave >> 5) & 31, z = (wave >> 10) & 31, b = wave >> 15;
    float g = gamma[lane], be = beta[lane];
    float hacc = 0.f, xacc = 0.f, cnt = 0.f;
    #pragma unroll
    for (int i = 0; i < 8; ++i) {
        int zz = 2*z + (i>>2), yy = 2*y + ((i>>1)&1), xx = 2*x + (i&1);
        int vox = ((b*64 + zz)*64 + yy)*64 + xx;
        int m = mask[vox];
        if (m != 0) {
            float val = feats[vox*64 + lane];
            float s1 = red64(val);
            float s2 = red64(val*val);
            float mu = s1 * (1.f/64.f);
            float var = fmaxf(s2 * (1.f/64.f) - mu*mu, 0.f);
            float h = (val - mu) * rsqrtf(var + EPS) * g + be;
            h = siluf(h);
            hacc += h; xacc += val; cnt += 1.f;
        }
    }
    float inv = 1.f / fmaxf(cnt, 1.f);
    long vp = ((long)(b*34 + z+1)*34 + (y+1))*34 + (x+1);
    h_ds_pad[vp*64 + lane] = f2b(hacc * inv);
    x_ds[(long)wave*64 + lane] = f2b(xacc * inv);
    if (lane == 0) cnt_out[wave] = cnt;
}

// ---- conv1: DMA-staged double-buffer, 4 blk/CU (r7-verified structure) ----
// block = 256 thr = 4 waves; C-tile M=128 (4 y-rows x 32 x), N=128 oc.
__global__ void __launch_bounds__(256, 4) k_conv1(
    const b16* __restrict__ inp,      // padded [b][34][34][34][64] bf16
    const b16* __restrict__ wt,       // [tap][icb][128 oc][32 ic] bf16
    const float* __restrict__ bias,
    const float* __restrict__ cnt,
    b16* __restrict__ h2out)          // padded bf16 out
{
    constexpr int IC = 64, ICB = 2, NK = 54;
    __shared__ b16 lA[2][4096];
    __shared__ b16 lB[2][4096];

    int bid = ((blockIdx.x & 7) << 7) | (blockIdx.x >> 3);   // XCD swizzle
    int y0 = (bid & 7) << 2;
    int z  = (bid >> 3) & 31;
    int b  = bid >> 8;
    int t  = threadIdx.x;
    int lane = t & 63;
    int w = t >> 6;
    int col = lane & 15;
    int quad = lane >> 4;

    const b16* gAsrc[2];
    const b16* gBsrc[2];
    {
        int vsub = lane >> 2;
        int s    = lane & 3;
        #pragma unroll
        for (int j = 0; j < 2; ++j) {
            int x  = j*16 + vsub;
            int cA = (s - (x >> 1)) & 3;
            gAsrc[j] = inp + ((long)((b*34 + z)*34 + (y0 + w))*34 + x)*IC + cA*8;
            int cB = (s - (vsub >> 1)) & 3;
            gBsrc[j] = wt + (w*32 + j*16 + vsub)*32 + cB*8;
        }
    }

    int so   = ((quad + (col>>1)) & 3) * 8;
    int aoff = w*1024 + col*32 + so;
    int boff = col*32 + so;

    v4f acc[2][8];
    #pragma unroll
    for (int tl=0;tl<2;++tl)
        #pragma unroll
        for (int n=0;n<8;++n) acc[tl][n] = (v4f){0.f,0.f,0.f,0.f};

    long offAn = 0;
    int icbn = 0, kxn = 0, kyn = 0;
    auto advance = [&]() {
        ++icbn; offAn += 32;
        if (icbn == ICB) {
            icbn = 0; ++kxn;
            if (kxn == 3) {
                kxn = 0; ++kyn;
                if (kyn == 3) { kyn = 0; offAn += (long)(34*34 - 2*34 - 3)*IC; }
                else          {           offAn += (long)(34 - 3)*IC; }
            }
        }
    };
    auto stage = [&](long offA, long offB, int buf) {
        #pragma unroll
        for (int j = 0; j < 2; ++j) {
            gll16(gAsrc[j] + offA, &lA[buf][w*1024 + j*512]);
            gll16(gBsrc[j] + offB, &lB[buf][w*1024 + j*512]);
        }
    };

    stage(0, 0, 0);
    advance();
    long offBn = 4096;
    __syncthreads();

    int cur = 0;
    for (int k = 0; k < NK; ++k) {
        if (k + 1 < NK) { stage(offAn, offBn, cur ^ 1); advance(); offBn += 4096; }
        v8s a0 = *(const v8s*)(&lA[cur][aoff]);
        v8s a1 = *(const v8s*)(&lA[cur][aoff + 512]);
        #pragma unroll
        for (int n = 0; n < 8; ++n) {
            v8s bb = *(const v8s*)(&lB[cur][n*512 + boff]);
            acc[0][n] = __builtin_amdgcn_mfma_f32_16x16x32_bf16(a0, bb, acc[0][n], 0,0,0);
            acc[1][n] = __builtin_amdgcn_mfma_f32_16x16x32_bf16(a1, bb, acc[1][n], 0,0,0);
        }
        __syncthreads();
        cur ^= 1;
    }

    int yrow = y0 + w;
    long cellrow = ((long)(b*32+z)*32 + yrow)*32;

    float bv[8];
    #pragma unroll
    for (int n=0;n<8;++n) bv[n] = bias[n*16+col];

    long prow = ((long)(b*34 + z+1)*34 + (yrow+1))*34 + 1;

    #pragma unroll
    for (int tl=0; tl<2; ++tl) {
        // bias + LN(128, no affine) + silu + mask -> padded bf16
        float s1[4], s2[4];
        #pragma unroll
        for (int r=0;r<4;++r){
            float a=0.f, q=0.f;
            #pragma unroll
            for (int n=0;n<8;++n){ float v = acc[tl][n][r] + bv[n]; a+=v; q+=v*v; }
            s1[r]=a; s2[r]=q;
        }
        #pragma unroll
        for (int off=1; off<16; off<<=1){
            #pragma unroll
            for (int r=0;r<4;++r){ s1[r]+=__shfl_xor(s1[r],off); s2[r]+=__shfl_xor(s2[r],off); }
        }
        #pragma unroll
        for (int r=0;r<4;++r){
            int row = quad*4 + r;
            int x = tl*16 + row;
            float c = cnt[cellrow + x];
            float mu = s1[r]*(1.f/128.f);
            float var = fmaxf(s2[r]*(1.f/128.f) - mu*mu, 0.f);
            float rs = rsqrtf(var + EPS);
            bool act = c > 0.f;
            #pragma unroll
            for (int n=0;n<8;++n){
                float v = acc[tl][n][r] + bv[n];
                float hv = act ? siluf((v-mu)*rs) : 0.f;
                h2out[(prow + x)*128 + n*16 + col] = f2b(hv);
            }
        }
    }
}

// ---- conv2: DMA-staged double-buffer, 4 blk/CU (r7-verified 2x8 shape) ----
// block = 256 thr = 4 waves; wave = 32 rows x 128 oc (low live-reg count;
// the r8 2x2 split held 8 v8s live under the 128-reg cap -> spilled -> reverted)
__global__ void __launch_bounds__(256, 4) k_conv2(
    const b16* __restrict__ inp,      // padded [b][34][34][34][128] bf16
    const b16* __restrict__ wt,       // [tap][icb][128 oc][32 ic] bf16
    const float* __restrict__ bias,
    const float* __restrict__ cnt,
    const b16* __restrict__ x_ds,     // [cell][64]
    const b16* __restrict__ wst,      // [128 oc][64 ic]
    const float* __restrict__ b_skip,
    float* __restrict__ out)          // fp32 [cell][128]
{
    constexpr int IC = 128, ICB = 4, NK = 108;
    __shared__ b16 lA[2][4096];
    __shared__ b16 lB[2][4096];

    int bid = ((blockIdx.x & 7) << 7) | (blockIdx.x >> 3);   // XCD swizzle
    int y0 = (bid & 7) << 2;
    int z  = (bid >> 3) & 31;
    int b  = bid >> 8;
    int t  = threadIdx.x;
    int lane = t & 63;
    int w = t >> 6;
    int col = lane & 15;
    int quad = lane >> 4;

    const b16* gAsrc[2];
    const b16* gBsrc[2];
    {
        int vsub = lane >> 2;
        int s    = lane & 3;
        #pragma unroll
        for (int j = 0; j < 2; ++j) {
            int x  = j*16 + vsub;
            int cA = (s - (x >> 1)) & 3;
            gAsrc[j] = inp + ((long)((b*34 + z)*34 + (y0 + w))*34 + x)*IC + cA*8;
            int cB = (s - (vsub >> 1)) & 3;
            gBsrc[j] = wt + (w*32 + j*16 + vsub)*32 + cB*8;
        }
    }

    int so   = ((quad + (col>>1)) & 3) * 8;
    int aoff = w*1024 + col*32 + so;
    int boff = col*32 + so;

    v4f acc[2][8];
    #pragma unroll
    for (int tl=0;tl<2;++tl)
        #pragma unroll
        for (int n=0;n<8;++n) acc[tl][n] = (v4f){0.f,0.f,0.f,0.f};

    long offAn = 0;
    int icbn = 0, kxn = 0, kyn = 0;
    auto advance = [&]() {
        ++icbn; offAn += 32;
        if (icbn == ICB) {
            icbn = 0; ++kxn;
            if (kxn == 3) {
                kxn = 0; ++kyn;
                if (kyn == 3) { kyn = 0; offAn += (long)(34*34 - 2*34 - 3)*IC; }
                else          {           offAn += (long)(34 - 3)*IC; }
            }
        }
    };
    auto stage = [&](long offA, long offB, int buf) {
        #pragma unroll
        for (int j = 0; j < 2; ++j) {
            gll16(gAsrc[j] + offA, &lA[buf][w*1024 + j*512]);
            gll16(gBsrc[j] + offB, &lB[buf][w*1024 + j*512]);
        }
    };

    stage(0, 0, 0);
    advance();
    long offBn = 4096;
    __syncthreads();

    int cur = 0;
    for (int k = 0; k < NK; ++k) {
        if (k + 1 < NK) { stage(offAn, offBn, cur ^ 1); advance(); offBn += 4096; }
        v8s a0 = *(const v8s*)(&lA[cur][aoff]);
        v8s a1 = *(const v8s*)(&lA[cur][aoff + 512]);
        #pragma unroll
        for (int n = 0; n < 8; ++n) {
            v8s bb = *(const v8s*)(&lB[cur][n*512 + boff]);
            acc[0][n] = __builtin_amdgcn_mfma_f32_16x16x32_bf16(a0, bb, acc[0][n], 0,0,0);
            acc[1][n] = __builtin_amdgcn_mfma_f32_16x16x32_bf16(a1, bb, acc[1][n], 0,0,0);
        }
        __syncthreads();
        cur ^= 1;
    }

    int yrow = y0 + w;
    long cellrow = ((long)(b*32+z)*32 + yrow)*32;

    // skip GEMM: x_ds[cell][64] @ wst[128][64]^T folded into accumulators
    {
        const b16* X0 = x_ds + (cellrow + col)*64 + quad*8;
        const b16* X1 = X0 + 16*64;
        const b16* WS = wst + col*64 + quad*8;
        #pragma unroll
        for (int s = 0; s < 2; ++s) {
            v8s a0 = *(const v8s*)(X0 + s*32);
            v8s a1 = *(const v8s*)(X1 + s*32);
            #pragma unroll
            for (int n=0;n<8;++n) {
                v8s bb = *(const v8s*)(WS + n*16*64 + s*32);
                acc[0][n] = __builtin_amdgcn_mfma_f32_16x16x32_bf16(a0, bb, acc[0][n], 0,0,0);
                acc[1][n] = __builtin_amdgcn_mfma_f32_16x16x32_bf16(a1, bb, acc[1][n], 0,0,0);
            }
        }
    }

    float bv[8];
    #pragma unroll
    for (int n=0;n<8;++n) bv[n] = bias[n*16+col] + b_skip[n*16+col];

    #pragma unroll
    for (int tl=0; tl<2; ++tl) {
        #pragma unroll
        for (int r=0;r<4;++r){
            int row = quad*4 + r;
            int x = tl*16 + row;
            float c = cnt[cellrow + x];
            bool act = c > 0.f;
            #pragma unroll
            for (int n=0;n<8;++n){
                float v = acc[tl][n][r] + bv[n];
                out[(cellrow + x)*128 + n*16 + col] = act ? v : 0.f;
            }
        }
    }
}

extern "C" void kernel_launch(void* const* d_in, const int* in_sizes, int n_in,
                              void* d_out, int out_size, void* d_ws, size_t ws_size,
                              hipStream_t stream) {
    const float* feats  = (const float*)d_in[0];
    const int*   mask   = (const int*)  d_in[1];
    const float* gamma1 = (const float*)d_in[2];
    const float* beta1  = (const float*)d_in[3];
    const float* w1     = (const float*)d_in[4];
    const float* b1     = (const float*)d_in[5];
    const float* w2     = (const float*)d_in[6];
    const float* b2     = (const float*)d_in[7];
    const float* w_skip = (const float*)d_in[8];
    const float* b_skip = (const float*)d_in[9];
    float* out = (float*)d_out;

    char* ws = (char*)d_ws;
    b16*   h_ds_pad = (b16*)(ws);                        // 4*34^3*64*2  = 20,123,648
    b16*   h2_pad   = (b16*)(ws + 20123648);             // 4*34^3*128*2 = 40,247,296
    b16*   x_ds     = (b16*)(ws + 60370944);             // 16,777,216
    float* cnt      = (float*)(ws + 77148160);           // 524,288
    b16*   w1t      = (b16*)(ws + 77672448);             // 442,368
    b16*   w2t      = (b16*)(ws + 78114816);             // 884,736
    b16*   wst      = (b16*)(ws + 78999552);             // 16,384

    // zero halos (interior fully overwritten each launch)
    hipMemsetAsync(h_ds_pad, 0, 20123648, stream);
    hipMemsetAsync(h2_pad,   0, 40247296, stream);

    const int n_w1 = 27*64*128;    // 221184
    const int n_w2 = 27*128*128;   // 442368
    const int n_ws = 64*128;       // 8192
    k_wtb<64> <<<(n_w1 + 255)/256, 256, 0, stream>>>(w1, w1t, n_w1);
    k_wtb<128><<<(n_w2 + 255)/256, 256, 0, stream>>>(w2, w2t, n_w2);
    k_wt<64>  <<<(n_ws + 255)/256, 256, 0, stream>>>(w_skip, wst, n_ws);

    k_ln_down<<<32768, 256, 0, stream>>>(feats, mask, gamma1, beta1, h_ds_pad, x_ds, cnt);

    k_conv1<<<1024, 256, 0, stream>>>(h_ds_pad, w1t, b1, cnt, h2_pad);
    k_conv2<<<1024, 256, 0, stream>>>(h2_pad, w2t, b2, cnt, x_ds, wst, b_skip, out);
}